// Round 18
// baseline (223.483 us; speedup 1.0000x reference)
//
#include <hip/hip_runtime.h>
#include <math.h>

typedef _Float16 f16x8 __attribute__((ext_vector_type(8)));
typedef _Float16 f16x4 __attribute__((ext_vector_type(4)));
typedef float f32x4 __attribute__((ext_vector_type(4)));

#define SEQ 2048
#define DM 1024
#define NH 16
#define HD 64
#define MTOT 4096   // batch*seq

#define NEG_BIG (-30000.0f)

// native v_exp_f32 (base-2) — __exp2f doesn't exist in HIP device code
__device__ __forceinline__ float ex2(float x) {
  return __builtin_amdgcn_exp2f(x);
}

__device__ __forceinline__ void gl_lds16(const _Float16* g, _Float16* l) {
  __builtin_amdgcn_global_load_lds(
      (const __attribute__((address_space(1))) unsigned int*)g,
      (__attribute__((address_space(3))) unsigned int*)l, 16, 0, 0);
}

// ---------------------------------------------------------------------------
// prep: z<4  -> transpose+convert weight mat z (fp32 [k][n] -> fp16 [n][k]);
//       z=4,5 -> convert x fp32->fp16 (chunk = (z-4)*256 + y*16 + x, 8192 el);
//       z=6  -> RoPE cos/sin table [2048 s][32 d2] f32 pairs (one thr/entry).
// grid (16,16,7), 256 thr. Table lives in d_out (fully overwritten by the
// out-projection afterwards), so no extra workspace is needed.
// ---------------------------------------------------------------------------
__global__ __launch_bounds__(256) void prep(const float* __restrict__ x,
                                            const float* __restrict__ qw,
                                            const float* __restrict__ kw,
                                            const float* __restrict__ vw,
                                            const float* __restrict__ ow,
                                            _Float16* __restrict__ x16,
                                            _Float16* __restrict__ wT,
                                            float* __restrict__ tb) {
  const int z = blockIdx.z;
  const int t = threadIdx.x;
  if (z == 6) {
    const int idx = (blockIdx.y * 16 + blockIdx.x) * 256 + t;  // 0..65535
    const int s = idx >> 5, d2 = idx & 31;
    const float inv = __powf(10000.0f, -(float)d2 * (1.0f / 32.0f));
    float c, sn;
    __sincosf((float)s * inv, &sn, &c);
    tb[2 * idx] = c;
    tb[2 * idx + 1] = sn;
    return;
  }
  if (z >= 4) {
    const int c = (z - 4) * 256 + blockIdx.y * 16 + blockIdx.x;
    const size_t base = (size_t)c * 8192;
#pragma unroll
    for (int rnd = 0; rnd < 4; ++rnd) {
      const size_t i = base + rnd * 2048 + t * 8;
      f32x4 a = *(const f32x4*)(x + i);
      f32x4 b = *(const f32x4*)(x + i + 4);
      f16x8 o;
#pragma unroll
      for (int j = 0; j < 4; ++j) { o[j] = (_Float16)a[j]; o[4 + j] = (_Float16)b[j]; }
      *(f16x8*)(x16 + i) = o;
    }
    return;
  }
  __shared__ float Ts[64][65];
  const float* srcs[4] = {qw, kw, vw, ow};
  const float* src = srcs[z];
  _Float16* dst = wT + (size_t)z * DM * DM;
  const int k0 = blockIdx.y * 64, n0 = blockIdx.x * 64;
  const int r = t >> 2, c4 = (t & 3) * 16;
  const float* sp = src + (size_t)(k0 + r) * DM + n0 + c4;
#pragma unroll
  for (int j = 0; j < 4; ++j) {
    f32x4 vv = *(const f32x4*)(sp + j * 4);
#pragma unroll
    for (int e = 0; e < 4; ++e) Ts[r][c4 + j * 4 + e] = vv[e];
  }
  __syncthreads();
  f16x8 o0, o1;
#pragma unroll
  for (int j = 0; j < 8; ++j) {
    o0[j] = (_Float16)Ts[c4 + j][r];
    o1[j] = (_Float16)Ts[c4 + 8 + j][r];
  }
  _Float16* dp = dst + (size_t)(n0 + r) * DM + k0 + c4;
  *(f16x8*)(dp) = o0;
  *(f16x8*)(dp + 8) = o1;
}

// ---------------------------------------------------------------------------
// Generic GEMM: Y = A(M,K) @ BT^T, BT fp16 [n][k]. Tile BM x BN, 2x2 waves.
// BK=64 via TWO parallel [rows][32] half-buffers (conflict-free 64-B rows;
// NOT the single [rows][64] layout — 128-B rows = 16-way conflict, measured).
// FUSED3: BT = 3 concatenated mats. ROPE on mats 0,1 via cos/sin TABLE.
// T1 XCD-chunked block remap (prologue-only, bijective when nwg%8==0).
// ---------------------------------------------------------------------------
template <int BM, int BN, bool FUSED3, bool OUTF32, bool ROPE>
__global__ __launch_bounds__(256) void gemm_t(const _Float16* __restrict__ A,
                                              const _Float16* __restrict__ BT,
                                              void* __restrict__ Yv,
                                              const float* __restrict__ Tb,
                                              int M, int K) {
  constexpr int WM = BM / 2, WN = BN / 2;
  constexpr int MI = WM / 16, NI = WN / 16;
  __shared__ _Float16 As[2][BM * 32];
  __shared__ _Float16 Bs[2][BN * 32];
  const int tid = threadIdx.x;
  const int lane = tid & 63;
  const int fl = lane & 15, fh = lane >> 4;
  const int wave = tid >> 6;

  // XCD-chunked swizzle (grids here are multiples of 8)
  const int nwg = gridDim.x * gridDim.y;
  int lin = blockIdx.y * gridDim.x + blockIdx.x;
  lin = (lin & 7) * (nwg >> 3) + (lin >> 3);
  const int bx = lin % gridDim.x;
  const int by = lin / gridDim.x;

  const int m0 = by * BM;
  int n0 = bx * BN;
  int mat = 0;
  const _Float16* Bp = BT;
  char* Yp = (char*)Yv;
  if (FUSED3) {
    mat = n0 >> 10;
    n0 &= 1023;
    Bp = BT + (size_t)mat * DM * DM;
    Yp += (size_t)mat * M * DM * (OUTF32 ? 4 : 2);
  }
  const int wm = (wave >> 1) * WM, wn = (wave & 1) * WN;

  // staging: one gl_lds16 covers 16 rows (64 lanes x 16B / 64B row)
  const int l4 = lane >> 2, lc = (lane & 3) * 8;

  f32x4 acc[MI][NI] = {};

  for (int k0 = 0; k0 < K; k0 += 64) {
    __syncthreads();
#pragma unroll
    for (int j = wave; j < BM / 16; j += 4) {
      const _Float16* ap = A + (size_t)(m0 + j * 16 + l4) * K + k0 + lc;
      gl_lds16(ap, &As[0][j * 16 * 32]);
      gl_lds16(ap + 32, &As[1][j * 16 * 32]);
    }
#pragma unroll
    for (int j = wave; j < BN / 16; j += 4) {
      const _Float16* bp = Bp + (size_t)(n0 + j * 16 + l4) * K + k0 + lc;
      gl_lds16(bp, &Bs[0][j * 16 * 32]);
      gl_lds16(bp + 32, &Bs[1][j * 16 * 32]);
    }
    __syncthreads();
#pragma unroll
    for (int h = 0; h < 2; ++h) {
      f16x8 af[MI], bf[NI];
#pragma unroll
      for (int mi = 0; mi < MI; ++mi)
        af[mi] = *(const f16x8*)(&As[h][(wm + mi * 16 + fl) * 32 + fh * 8]);
#pragma unroll
      for (int ni = 0; ni < NI; ++ni)
        bf[ni] = *(const f16x8*)(&Bs[h][(wn + ni * 16 + fl) * 32 + fh * 8]);
#pragma unroll
      for (int mi = 0; mi < MI; ++mi)
#pragma unroll
        for (int ni = 0; ni < NI; ++ni)
          acc[mi][ni] = __builtin_amdgcn_mfma_f32_16x16x32_f16(af[mi], bf[ni], acc[mi][ni], 0, 0, 0);
    }
  }

  // C/D: row = fh*4 + r, col = fl
#pragma unroll
  for (int mi = 0; mi < MI; ++mi)
#pragma unroll
    for (int ni = 0; ni < NI; ++ni) {
      const int gm = m0 + wm + mi * 16 + fh * 4;
      const int gn = n0 + wn + ni * 16 + fl;
      if (ROPE && mat < 2) {
        const int d2 = (gn & 63) >> 1;
        const float sgn = (gn & 1) ? 1.0f : -1.0f;
#pragma unroll
        for (int r = 0; r < 4; ++r) {
          const int s = (gm + r) & (SEQ - 1);
          const float2 cs = *(const float2*)(Tb + (size_t)((s << 5) + d2) * 2);
          const float v = acc[mi][ni][r];
          const float p = __shfl_xor(v, 1, 64);
          acc[mi][ni][r] = v * cs.x + sgn * p * cs.y;
        }
      }
#pragma unroll
      for (int r = 0; r < 4; ++r) {
        if (OUTF32)
          ((float*)Yp)[(size_t)(gm + r) * DM + gn] = acc[mi][ni][r];
        else
          ((_Float16*)Yp)[(size_t)(gm + r) * DM + gn] = (_Float16)acc[mi][ni][r];
      }
    }
}

// ---------------------------------------------------------------------------
// Attention pieces (S^T formulation, exp2 domain). S^T = K·Q^T via 16x16x32;
// C-layout of S^T (kv=fh*4+r, q=fl) IS the B-frag layout of 16x16x16 MFMA,
// so P^T feeds O^T = V^T·P^T straight from registers — no LDS round-trip.
// Q pre-scaled by (1/sqrt(dm))*log2(e): softmax in base-2 (native v_exp_f32).
// Defer threshold 11.5 (log2 units; P bounded by 2^11.5 ~ 2896, fp16-safe).
// LDS bank hygiene (both strides ≡ 6 mod 32 in dwords):
//  - Vt stride 140 el (70 dw): PV f16x4 reads tile all 32 banks once per
//    quarter-wave (conflicts 4.9M -> 1.6M measured, round 8).
//  - Ks stride 76 el (38 dw, round 18): QK b128 reads get bank-start
//    6*fl + 4*fh — 6*fl takes each even residue exactly once over fl=0..15,
//    so the wave tiles banks at the free 2/bank minimum. The old stride 72
//    (36 dw ≡ 4) put fl and fl+8 in the same 4-bank window: 2-way serialize
//    on every QK read = the residual 1.6M conflict cycles.
// Micro-opts (register-neutral): max3-fusable reduce tree; cvt_pkrtz packed
// f32->f16 (static_cast<_Float16> needed — __fp16 vec, round-13 lesson);
// rs split accumulators.
// ATTN INNER LOOP FROZEN. VGPR lessons (rounds 4/6/9/10/16): 512-thr blocks
// hard-capped at 128 VGPRs; serial structure = 120-124. Every live-state
// ADDITION spilled (WRITE_SIZE 8192 -> 11-148 MB) — and round 16 showed even
// REMOVING the serial max chain spills: the chain is a natural scheduling
// fence; without it the scheduler extends s[]/pb[] live ranges past the cap.
// Do not touch.
// ---------------------------------------------------------------------------
__device__ __forceinline__ void qk_tile(const _Float16 (*Ks)[76],
                                        const f16x8 qf[2], f32x4 s[8],
                                        int fl, int fh) {
#pragma unroll
  for (int t = 0; t < 8; ++t) {
    f16x8 kf0 = *(const f16x8*)(&Ks[t * 16 + fl][fh * 8]);
    f16x8 kf1 = *(const f16x8*)(&Ks[t * 16 + fl][32 + fh * 8]);
    f32x4 z = {0.f, 0.f, 0.f, 0.f};
    z = __builtin_amdgcn_mfma_f32_16x16x32_f16(kf0, qf[0], z, 0, 0, 0);
    z = __builtin_amdgcn_mfma_f32_16x16x32_f16(kf1, qf[1], z, 0, 0, 0);
    s[t] = z;
  }
}

__device__ __forceinline__ void sm_pv(const _Float16 (*Vt)[140], f32x4 s[8],
                                      f32x4 o_acc[4], float& m_r, float& l_r,
                                      int kv0, int qg, bool do_mask, int fl,
                                      int fh) {
  if (do_mask) {
#pragma unroll
    for (int t = 0; t < 8; ++t)
#pragma unroll
      for (int r = 0; r < 4; ++r)
        if (kv0 + t * 16 + fh * 4 + r > qg) s[t][r] = NEG_BIG;
  }
  // max3-fusable tree: per tile max3+max (2 instrs), then tree-combine.
  float tm[8];
#pragma unroll
  for (int t = 0; t < 8; ++t)
    tm[t] = fmaxf(fmaxf(fmaxf(s[t][0], s[t][1]), s[t][2]), s[t][3]);
  float mx = fmaxf(fmaxf(fmaxf(tm[0], tm[1]), tm[2]),
                   fmaxf(fmaxf(tm[3], tm[4]), tm[5]));
  mx = fmaxf(fmaxf(mx, tm[6]), tm[7]);
  mx = fmaxf(mx, __shfl_xor(mx, 16, 64));
  mx = fmaxf(mx, __shfl_xor(mx, 32, 64));
  // T13 defer-max (log2 domain)
  float mn = m_r;
  if (__any(mx > m_r + 11.5f)) {
    mn = fmaxf(m_r, mx);
    const float a = ex2(m_r - mn);
    l_r *= a;
#pragma unroll
    for (int mt = 0; mt < 4; ++mt)
#pragma unroll
      for (int r = 0; r < 4; ++r) o_acc[mt][r] *= a;
    m_r = mn;
  }
  float rs0 = 0.f, rs1 = 0.f;
  f16x4 pb[8];
#pragma unroll
  for (int t = 0; t < 8; ++t) {
    const float p0 = ex2(s[t][0] - mn);
    const float p1 = ex2(s[t][1] - mn);
    const float p2 = ex2(s[t][2] - mn);
    const float p3 = ex2(s[t][3] - mn);
    rs0 += p0 + p1;
    rs1 += p2 + p3;
    const auto lo = __builtin_amdgcn_cvt_pkrtz(p0, p1);  // v_cvt_pkrtz_f16_f32
    const auto hi = __builtin_amdgcn_cvt_pkrtz(p2, p3);
    f16x4 pk = {static_cast<_Float16>(lo[0]), static_cast<_Float16>(lo[1]),
                static_cast<_Float16>(hi[0]), static_cast<_Float16>(hi[1])};
    pb[t] = pk;
  }
  float rs = rs0 + rs1;
  rs += __shfl_xor(rs, 16, 64);
  rs += __shfl_xor(rs, 32, 64);
  l_r += rs;
#pragma unroll
  for (int mt = 0; mt < 4; ++mt)
#pragma unroll
    for (int t = 0; t < 8; ++t) {
      f16x4 va = *(const f16x4*)(&Vt[mt * 16 + fl][t * 16 + fh * 4]);
      o_acc[mt] = __builtin_amdgcn_mfma_f32_16x16x16f16(va, pb[t], o_acc[mt], 0, 0, 0);
    }
}

// ---------------------------------------------------------------------------
// Flash attention, causal, diagonally paired: work unit w handles q-stripes p
// and 15-p (constant 17 compute-units/block, no tail; KV chunk staged once for
// both). 512 thr = 8 waves, 16 q/wave/stripe. Grid (8, 32).
// DOUBLE-BUFFERED K/V LDS (round 15, measured 52.8 -> 49.3 us): ONE barrier
// per chunk. barrier -> issue loads(c+1) -> compute buf[c&1] -> write(c+1)
// into buf[(c+1)&1]. LDS 74.8 KB (1 block/CU — grid is 1/CU anyway).
// T1 XCD remap; T14 prefetch. VGPR budget note above still applies.
// ---------------------------------------------------------------------------
__global__ __launch_bounds__(512) void attn_kernel(const _Float16* __restrict__ Q,
                                                   const _Float16* __restrict__ K,
                                                   const _Float16* __restrict__ V,
                                                   _Float16* __restrict__ O) {
  __shared__ _Float16 Ks[2][128][76];   // [buf][kv][d], stride 76 (bank-clean)
  __shared__ _Float16 Vt[2][64][140];   // [buf][d][kv], stride 140 (bank-clean)

  const int tid = threadIdx.x;
  const int lane = tid & 63;
  const int fl = lane & 15, fh = lane >> 4;
  const int wave = tid >> 6;
  const int lin = blockIdx.y * 8 + blockIdx.x;      // dispatch linear id
  const int w = (lin & 7) * 32 + (lin >> 3);        // XCD-chunked remap (bijective)
  const int p = w & 7;                              // 0..7
  const int bh = w >> 3;                            // 0..31
  const int b = bh >> 4, h = bh & 15;
  const int qt_lo = p * 128 + wave * 16;
  const int qt_hi = (15 - p) * 128 + wave * 16;

  const _Float16* Qb = Q + (size_t)b * SEQ * DM + h * HD;
  const _Float16* Kb = K + (size_t)b * SEQ * DM + h * HD;
  const _Float16* Vb = V + (size_t)b * SEQ * DM + h * HD;

  // 1/sqrt(1024) * log2(e): softmax in exp2 domain
  const _Float16 hs = (_Float16)(0.03125f * 1.44269504f);
  f16x8 qlo[2], qhi[2];
#pragma unroll
  for (int kh = 0; kh < 2; ++kh) {
    qlo[kh] = *(const f16x8*)(Qb + (size_t)(qt_lo + fl) * DM + kh * 32 + fh * 8);
    qhi[kh] = *(const f16x8*)(Qb + (size_t)(qt_hi + fl) * DM + kh * 32 + fh * 8);
#pragma unroll
    for (int j = 0; j < 8; ++j) { qlo[kh][j] *= hs; qhi[kh][j] *= hs; }
  }

  f32x4 o_lo[4] = {}, o_hi[4] = {};
  float m_lo = NEG_BIG, l_lo = 0.f, m_hi = NEG_BIG, l_hi = 0.f;

  const int sr = tid >> 3, e = tid & 7, sc8 = e * 8;
  const int cmax = 15 - p;

  // prologue: load chunk 0 and stage it into buf 0
  f16x8 k0v = *(const f16x8*)(Kb + (size_t)(sr) * DM + sc8);
  f16x8 k1v = *(const f16x8*)(Kb + (size_t)(64 + sr) * DM + sc8);
  f16x8 v0v = *(const f16x8*)(Vb + (size_t)(sr) * DM + sc8);
  f16x8 v1v = *(const f16x8*)(Vb + (size_t)(64 + sr) * DM + sc8);
  *(f16x8*)(&Ks[0][sr][sc8]) = k0v;
  *(f16x8*)(&Ks[0][64 + sr][sc8]) = k1v;
#pragma unroll
  for (int t = 0; t < 8; ++t) {
    const int jj = (t + e) & 7;       // 2 lanes share a dword: free 2-way
    Vt[0][sc8 + jj][sr] = v0v[jj];
    Vt[0][sc8 + jj][64 + sr] = v1v[jj];
  }

  for (int c = 0; c <= cmax; ++c) {
    const int buf = c & 1;
    const int kv0 = c * 128;
    __syncthreads();                  // buf[c&1] writes visible to all waves

    if (c < cmax) {  // T14: issue next chunk's loads; land under compute
      const int kn = kv0 + 128;
      k0v = *(const f16x8*)(Kb + (size_t)(kn + sr) * DM + sc8);
      k1v = *(const f16x8*)(Kb + (size_t)(kn + 64 + sr) * DM + sc8);
      v0v = *(const f16x8*)(Vb + (size_t)(kn + sr) * DM + sc8);
      v1v = *(const f16x8*)(Vb + (size_t)(kn + 64 + sr) * DM + sc8);
    }

    {
      f32x4 s[8];
      qk_tile(Ks[buf], qhi, s, fl, fh);
      sm_pv(Vt[buf], s, o_hi, m_hi, l_hi, kv0, qt_hi + fl, c == cmax, fl, fh);
    }
    if (c <= p) {
      f32x4 s[8];
      qk_tile(Ks[buf], qlo, s, fl, fh);
      sm_pv(Vt[buf], s, o_lo, m_lo, l_lo, kv0, qt_lo + fl, c == p, fl, fh);
    }

    if (c < cmax) {  // stage chunk c+1 into the alternate buffer
      const int nb = buf ^ 1;
      *(f16x8*)(&Ks[nb][sr][sc8]) = k0v;
      *(f16x8*)(&Ks[nb][64 + sr][sc8]) = k1v;
#pragma unroll
      for (int t = 0; t < 8; ++t) {
        const int jj = (t + e) & 7;
        Vt[nb][sc8 + jj][sr] = v0v[jj];
        Vt[nb][sc8 + jj][64 + sr] = v1v[jj];
      }
    }
  }

  // epilogue: O[q][d] from O^T C-layout (d = mt*16 + fh*4 + r contiguous in r)
  {
    const float il = 1.0f / l_lo;
    _Float16* Op = O + ((size_t)b * SEQ + qt_lo + fl) * DM + h * HD;
#pragma unroll
    for (int mt = 0; mt < 4; ++mt) {
      f16x4 ov = {(_Float16)(o_lo[mt][0] * il), (_Float16)(o_lo[mt][1] * il),
                  (_Float16)(o_lo[mt][2] * il), (_Float16)(o_lo[mt][3] * il)};
      *(f16x4*)(Op + mt * 16 + fh * 4) = ov;
    }
  }
  {
    const float il = 1.0f / l_hi;
    _Float16* Op = O + ((size_t)b * SEQ + qt_hi + fl) * DM + h * HD;
#pragma unroll
    for (int mt = 0; mt < 4; ++mt) {
      f16x4 ov = {(_Float16)(o_hi[mt][0] * il), (_Float16)(o_hi[mt][1] * il),
                  (_Float16)(o_hi[mt][2] * il), (_Float16)(o_hi[mt][3] * il)};
      *(f16x4*)(Op + mt * 16 + fh * 4) = ov;
    }
  }
}

// ---------------------------------------------------------------------------
extern "C" void kernel_launch(void* const* d_in, const int* in_sizes, int n_in,
                              void* d_out, int out_size, void* d_ws, size_t ws_size,
                              hipStream_t stream) {
  const float* x = (const float*)d_in[0];
  const float* qw = (const float*)d_in[1];
  const float* kw = (const float*)d_in[2];
  const float* vw = (const float*)d_in[3];
  const float* ow = (const float*)d_in[4];
  float* out = (float*)d_out;

  const size_t MD = (size_t)MTOT * DM;  // 4M elements
  _Float16* x16 = (_Float16*)d_ws;      // [0, 4M) ; later reused as attention M
  _Float16* wT = x16 + MD;              // [4M, 8M): qwT,kwT,vwT,owT
  _Float16* Qw = wT + 4 * (size_t)DM * DM;  // [8M, 12M)
  _Float16* Kw = Qw + MD;               // [12M, 16M)
  _Float16* Vw = Kw + MD;               // [16M, 20M)
  _Float16* Mw = x16;                   // attention output reuses x16
  float* tb = out;                      // RoPE table borrows d_out (512 KB);
                                        // out-proj later overwrites all of out

  prep<<<dim3(16, 16, 7), 256, 0, stream>>>(x, qw, kw, vw, ow, x16, wT, tb);

  // Fused QKV (N = 3072) with RoPE applied to Q,K in the epilogue (table)
  gemm_t<128, 128, true, false, true><<<dim3(24, MTOT / 128), 256, 0, stream>>>(
      x16, wT, Qw, tb, MTOT, DM);

  attn_kernel<<<dim3(8, 32), 512, 0, stream>>>(Qw, Kw, Vw, Mw);

  // Out projection: 64x128 tiles -> 512 blocks (2/CU)
  gemm_t<64, 128, false, true, false><<<dim3(8, MTOT / 64), 256, 0, stream>>>(
      Mw, wT + 3 * (size_t)DM * DM, out, nullptr, MTOT, DM);
}

// Round 19
// 177.017 us; speedup vs baseline: 1.2625x; 1.2625x over previous
//
#include <hip/hip_runtime.h>
#include <math.h>

typedef _Float16 f16x8 __attribute__((ext_vector_type(8)));
typedef _Float16 f16x4 __attribute__((ext_vector_type(4)));
typedef float f32x4 __attribute__((ext_vector_type(4)));

#define SEQ 2048
#define DM 1024
#define NH 16
#define HD 64
#define MTOT 4096   // batch*seq

#define NEG_BIG (-30000.0f)

// native v_exp_f32 (base-2) — __exp2f doesn't exist in HIP device code
__device__ __forceinline__ float ex2(float x) {
  return __builtin_amdgcn_exp2f(x);
}

__device__ __forceinline__ void gl_lds16(const _Float16* g, _Float16* l) {
  __builtin_amdgcn_global_load_lds(
      (const __attribute__((address_space(1))) unsigned int*)g,
      (__attribute__((address_space(3))) unsigned int*)l, 16, 0, 0);
}

// ---------------------------------------------------------------------------
// prep: z<4  -> transpose+convert weight mat z (fp32 [k][n] -> fp16 [n][k]);
//       z=4,5 -> convert x fp32->fp16 (chunk = (z-4)*256 + y*16 + x, 8192 el);
//       z=6  -> RoPE cos/sin table [2048 s][32 d2] f32 pairs (one thr/entry).
// grid (16,16,7), 256 thr. Table lives in d_out (fully overwritten by the
// out-projection afterwards), so no extra workspace is needed.
// ---------------------------------------------------------------------------
__global__ __launch_bounds__(256) void prep(const float* __restrict__ x,
                                            const float* __restrict__ qw,
                                            const float* __restrict__ kw,
                                            const float* __restrict__ vw,
                                            const float* __restrict__ ow,
                                            _Float16* __restrict__ x16,
                                            _Float16* __restrict__ wT,
                                            float* __restrict__ tb) {
  const int z = blockIdx.z;
  const int t = threadIdx.x;
  if (z == 6) {
    const int idx = (blockIdx.y * 16 + blockIdx.x) * 256 + t;  // 0..65535
    const int s = idx >> 5, d2 = idx & 31;
    const float inv = __powf(10000.0f, -(float)d2 * (1.0f / 32.0f));
    float c, sn;
    __sincosf((float)s * inv, &sn, &c);
    tb[2 * idx] = c;
    tb[2 * idx + 1] = sn;
    return;
  }
  if (z >= 4) {
    const int c = (z - 4) * 256 + blockIdx.y * 16 + blockIdx.x;
    const size_t base = (size_t)c * 8192;
#pragma unroll
    for (int rnd = 0; rnd < 4; ++rnd) {
      const size_t i = base + rnd * 2048 + t * 8;
      f32x4 a = *(const f32x4*)(x + i);
      f32x4 b = *(const f32x4*)(x + i + 4);
      f16x8 o;
#pragma unroll
      for (int j = 0; j < 4; ++j) { o[j] = (_Float16)a[j]; o[4 + j] = (_Float16)b[j]; }
      *(f16x8*)(x16 + i) = o;
    }
    return;
  }
  __shared__ float Ts[64][65];
  const float* srcs[4] = {qw, kw, vw, ow};
  const float* src = srcs[z];
  _Float16* dst = wT + (size_t)z * DM * DM;
  const int k0 = blockIdx.y * 64, n0 = blockIdx.x * 64;
  const int r = t >> 2, c4 = (t & 3) * 16;
  const float* sp = src + (size_t)(k0 + r) * DM + n0 + c4;
#pragma unroll
  for (int j = 0; j < 4; ++j) {
    f32x4 vv = *(const f32x4*)(sp + j * 4);
#pragma unroll
    for (int e = 0; e < 4; ++e) Ts[r][c4 + j * 4 + e] = vv[e];
  }
  __syncthreads();
  f16x8 o0, o1;
#pragma unroll
  for (int j = 0; j < 8; ++j) {
    o0[j] = (_Float16)Ts[c4 + j][r];
    o1[j] = (_Float16)Ts[c4 + 8 + j][r];
  }
  _Float16* dp = dst + (size_t)(n0 + r) * DM + k0 + c4;
  *(f16x8*)(dp) = o0;
  *(f16x8*)(dp + 8) = o1;
}

// ---------------------------------------------------------------------------
// Generic GEMM: Y = A(M,K) @ BT^T, BT fp16 [n][k]. Tile BM x BN, 2x2 waves.
// BK=64 via TWO parallel [rows][32] half-buffers (conflict-free 64-B rows;
// NOT the single [rows][64] layout — 128-B rows = 16-way conflict, measured).
// FUSED3: BT = 3 concatenated mats. ROPE on mats 0,1 via cos/sin TABLE.
// T1 XCD-chunked block remap (prologue-only, bijective when nwg%8==0).
// ---------------------------------------------------------------------------
template <int BM, int BN, bool FUSED3, bool OUTF32, bool ROPE>
__global__ __launch_bounds__(256) void gemm_t(const _Float16* __restrict__ A,
                                              const _Float16* __restrict__ BT,
                                              void* __restrict__ Yv,
                                              const float* __restrict__ Tb,
                                              int M, int K) {
  constexpr int WM = BM / 2, WN = BN / 2;
  constexpr int MI = WM / 16, NI = WN / 16;
  __shared__ _Float16 As[2][BM * 32];
  __shared__ _Float16 Bs[2][BN * 32];
  const int tid = threadIdx.x;
  const int lane = tid & 63;
  const int fl = lane & 15, fh = lane >> 4;
  const int wave = tid >> 6;

  // XCD-chunked swizzle (grids here are multiples of 8)
  const int nwg = gridDim.x * gridDim.y;
  int lin = blockIdx.y * gridDim.x + blockIdx.x;
  lin = (lin & 7) * (nwg >> 3) + (lin >> 3);
  const int bx = lin % gridDim.x;
  const int by = lin / gridDim.x;

  const int m0 = by * BM;
  int n0 = bx * BN;
  int mat = 0;
  const _Float16* Bp = BT;
  char* Yp = (char*)Yv;
  if (FUSED3) {
    mat = n0 >> 10;
    n0 &= 1023;
    Bp = BT + (size_t)mat * DM * DM;
    Yp += (size_t)mat * M * DM * (OUTF32 ? 4 : 2);
  }
  const int wm = (wave >> 1) * WM, wn = (wave & 1) * WN;

  // staging: one gl_lds16 covers 16 rows (64 lanes x 16B / 64B row)
  const int l4 = lane >> 2, lc = (lane & 3) * 8;

  f32x4 acc[MI][NI] = {};

  for (int k0 = 0; k0 < K; k0 += 64) {
    __syncthreads();
#pragma unroll
    for (int j = wave; j < BM / 16; j += 4) {
      const _Float16* ap = A + (size_t)(m0 + j * 16 + l4) * K + k0 + lc;
      gl_lds16(ap, &As[0][j * 16 * 32]);
      gl_lds16(ap + 32, &As[1][j * 16 * 32]);
    }
#pragma unroll
    for (int j = wave; j < BN / 16; j += 4) {
      const _Float16* bp = Bp + (size_t)(n0 + j * 16 + l4) * K + k0 + lc;
      gl_lds16(bp, &Bs[0][j * 16 * 32]);
      gl_lds16(bp + 32, &Bs[1][j * 16 * 32]);
    }
    __syncthreads();
#pragma unroll
    for (int h = 0; h < 2; ++h) {
      f16x8 af[MI], bf[NI];
#pragma unroll
      for (int mi = 0; mi < MI; ++mi)
        af[mi] = *(const f16x8*)(&As[h][(wm + mi * 16 + fl) * 32 + fh * 8]);
#pragma unroll
      for (int ni = 0; ni < NI; ++ni)
        bf[ni] = *(const f16x8*)(&Bs[h][(wn + ni * 16 + fl) * 32 + fh * 8]);
#pragma unroll
      for (int mi = 0; mi < MI; ++mi)
#pragma unroll
        for (int ni = 0; ni < NI; ++ni)
          acc[mi][ni] = __builtin_amdgcn_mfma_f32_16x16x32_f16(af[mi], bf[ni], acc[mi][ni], 0, 0, 0);
    }
  }

  // C/D: row = fh*4 + r, col = fl
#pragma unroll
  for (int mi = 0; mi < MI; ++mi)
#pragma unroll
    for (int ni = 0; ni < NI; ++ni) {
      const int gm = m0 + wm + mi * 16 + fh * 4;
      const int gn = n0 + wn + ni * 16 + fl;
      if (ROPE && mat < 2) {
        const int d2 = (gn & 63) >> 1;
        const float sgn = (gn & 1) ? 1.0f : -1.0f;
#pragma unroll
        for (int r = 0; r < 4; ++r) {
          const int s = (gm + r) & (SEQ - 1);
          const float2 cs = *(const float2*)(Tb + (size_t)((s << 5) + d2) * 2);
          const float v = acc[mi][ni][r];
          const float p = __shfl_xor(v, 1, 64);
          acc[mi][ni][r] = v * cs.x + sgn * p * cs.y;
        }
      }
#pragma unroll
      for (int r = 0; r < 4; ++r) {
        if (OUTF32)
          ((float*)Yp)[(size_t)(gm + r) * DM + gn] = acc[mi][ni][r];
        else
          ((_Float16*)Yp)[(size_t)(gm + r) * DM + gn] = (_Float16)acc[mi][ni][r];
      }
    }
}

// ---------------------------------------------------------------------------
// Attention pieces (S^T formulation, exp2 domain). S^T = K·Q^T via 16x16x32;
// C-layout of S^T (kv=fh*4+r, q=fl) IS the B-frag layout of 16x16x16 MFMA,
// so P^T feeds O^T = V^T·P^T straight from registers — no LDS round-trip.
// Q pre-scaled by (1/sqrt(dm))*log2(e): softmax in base-2 (native v_exp_f32).
// Defer threshold 11.5 (log2 units; P bounded by 2^11.5 ~ 2896, fp16-safe).
// LDS layout (hard-won):
//  - Vt stride 140 el (70 dw ≡ 6 mod 32): PV f16x4 reads tile all 32 banks
//    once per quarter-wave (conflicts 4.9M -> 1.6M measured, round 8).
//  - Ks stride 72 el: residual 1.6M 2-way conflicts on QK b128 reads (~5% of
//    cycles) are ACCEPTED. Round 18 tried stride 76 (bank-perfect ≡6): rows
//    lose 16-B alignment -> compiler splits every b128 read -> 2x SLOWDOWN
//    (95 us, conflicts 0). RULE: b128-read strides must be multiples of
//    8 elements; aligned strides can only hit residues {0,4,8,...} mod 32,
//    so ≡6 is unreachable without a full XOR-swizzle restructure.
// Micro-opts (register-neutral): max3-fusable reduce tree; cvt_pkrtz packed
// f32->f16 (static_cast<_Float16> needed — __fp16 vec, round-13 lesson);
// rs split accumulators.
// ATTN INNER LOOP FROZEN. VGPR lessons (rounds 4/6/9/10/16): 512-thr blocks
// hard-capped at 128 VGPRs; serial structure = 120-124. Every live-state
// ADDITION spilled (WRITE_SIZE 8192 -> 11-148 MB) — and round 16 showed even
// REMOVING the serial max chain spills: the chain is a natural scheduling
// fence; without it the scheduler extends s[]/pb[] live ranges past the cap.
// Do not touch.
// ---------------------------------------------------------------------------
__device__ __forceinline__ void qk_tile(const _Float16 (*Ks)[72],
                                        const f16x8 qf[2], f32x4 s[8],
                                        int fl, int fh) {
#pragma unroll
  for (int t = 0; t < 8; ++t) {
    f16x8 kf0 = *(const f16x8*)(&Ks[t * 16 + fl][fh * 8]);
    f16x8 kf1 = *(const f16x8*)(&Ks[t * 16 + fl][32 + fh * 8]);
    f32x4 z = {0.f, 0.f, 0.f, 0.f};
    z = __builtin_amdgcn_mfma_f32_16x16x32_f16(kf0, qf[0], z, 0, 0, 0);
    z = __builtin_amdgcn_mfma_f32_16x16x32_f16(kf1, qf[1], z, 0, 0, 0);
    s[t] = z;
  }
}

__device__ __forceinline__ void sm_pv(const _Float16 (*Vt)[140], f32x4 s[8],
                                      f32x4 o_acc[4], float& m_r, float& l_r,
                                      int kv0, int qg, bool do_mask, int fl,
                                      int fh) {
  if (do_mask) {
#pragma unroll
    for (int t = 0; t < 8; ++t)
#pragma unroll
      for (int r = 0; r < 4; ++r)
        if (kv0 + t * 16 + fh * 4 + r > qg) s[t][r] = NEG_BIG;
  }
  // max3-fusable tree: per tile max3+max (2 instrs), then tree-combine.
  float tm[8];
#pragma unroll
  for (int t = 0; t < 8; ++t)
    tm[t] = fmaxf(fmaxf(fmaxf(s[t][0], s[t][1]), s[t][2]), s[t][3]);
  float mx = fmaxf(fmaxf(fmaxf(tm[0], tm[1]), tm[2]),
                   fmaxf(fmaxf(tm[3], tm[4]), tm[5]));
  mx = fmaxf(fmaxf(mx, tm[6]), tm[7]);
  mx = fmaxf(mx, __shfl_xor(mx, 16, 64));
  mx = fmaxf(mx, __shfl_xor(mx, 32, 64));
  // T13 defer-max (log2 domain)
  float mn = m_r;
  if (__any(mx > m_r + 11.5f)) {
    mn = fmaxf(m_r, mx);
    const float a = ex2(m_r - mn);
    l_r *= a;
#pragma unroll
    for (int mt = 0; mt < 4; ++mt)
#pragma unroll
      for (int r = 0; r < 4; ++r) o_acc[mt][r] *= a;
    m_r = mn;
  }
  float rs0 = 0.f, rs1 = 0.f;
  f16x4 pb[8];
#pragma unroll
  for (int t = 0; t < 8; ++t) {
    const float p0 = ex2(s[t][0] - mn);
    const float p1 = ex2(s[t][1] - mn);
    const float p2 = ex2(s[t][2] - mn);
    const float p3 = ex2(s[t][3] - mn);
    rs0 += p0 + p1;
    rs1 += p2 + p3;
    const auto lo = __builtin_amdgcn_cvt_pkrtz(p0, p1);  // v_cvt_pkrtz_f16_f32
    const auto hi = __builtin_amdgcn_cvt_pkrtz(p2, p3);
    f16x4 pk = {static_cast<_Float16>(lo[0]), static_cast<_Float16>(lo[1]),
                static_cast<_Float16>(hi[0]), static_cast<_Float16>(hi[1])};
    pb[t] = pk;
  }
  float rs = rs0 + rs1;
  rs += __shfl_xor(rs, 16, 64);
  rs += __shfl_xor(rs, 32, 64);
  l_r += rs;
#pragma unroll
  for (int mt = 0; mt < 4; ++mt)
#pragma unroll
    for (int t = 0; t < 8; ++t) {
      f16x4 va = *(const f16x4*)(&Vt[mt * 16 + fl][t * 16 + fh * 4]);
      o_acc[mt] = __builtin_amdgcn_mfma_f32_16x16x16f16(va, pb[t], o_acc[mt], 0, 0, 0);
    }
}

// ---------------------------------------------------------------------------
// Flash attention, causal, diagonally paired: work unit w handles q-stripes p
// and 15-p (constant 17 compute-units/block, no tail; KV chunk staged once for
// both). 512 thr = 8 waves, 16 q/wave/stripe. Grid (8, 32).
// DOUBLE-BUFFERED K/V LDS (round 15, measured 52.8 -> 49.3 us): ONE barrier
// per chunk. barrier -> issue loads(c+1) -> compute buf[c&1] -> write(c+1)
// into buf[(c+1)&1]. LDS 71 KB (1 block/CU — grid is 1/CU anyway).
// T1 XCD remap; T14 prefetch. VGPR budget note above still applies.
// ---------------------------------------------------------------------------
__global__ __launch_bounds__(512) void attn_kernel(const _Float16* __restrict__ Q,
                                                   const _Float16* __restrict__ K,
                                                   const _Float16* __restrict__ V,
                                                   _Float16* __restrict__ O) {
  __shared__ _Float16 Ks[2][128][72];   // [buf][kv][d]
  __shared__ _Float16 Vt[2][64][140];   // [buf][d][kv], stride 140 (bank-clean)

  const int tid = threadIdx.x;
  const int lane = tid & 63;
  const int fl = lane & 15, fh = lane >> 4;
  const int wave = tid >> 6;
  const int lin = blockIdx.y * 8 + blockIdx.x;      // dispatch linear id
  const int w = (lin & 7) * 32 + (lin >> 3);        // XCD-chunked remap (bijective)
  const int p = w & 7;                              // 0..7
  const int bh = w >> 3;                            // 0..31
  const int b = bh >> 4, h = bh & 15;
  const int qt_lo = p * 128 + wave * 16;
  const int qt_hi = (15 - p) * 128 + wave * 16;

  const _Float16* Qb = Q + (size_t)b * SEQ * DM + h * HD;
  const _Float16* Kb = K + (size_t)b * SEQ * DM + h * HD;
  const _Float16* Vb = V + (size_t)b * SEQ * DM + h * HD;

  // 1/sqrt(1024) * log2(e): softmax in exp2 domain
  const _Float16 hs = (_Float16)(0.03125f * 1.44269504f);
  f16x8 qlo[2], qhi[2];
#pragma unroll
  for (int kh = 0; kh < 2; ++kh) {
    qlo[kh] = *(const f16x8*)(Qb + (size_t)(qt_lo + fl) * DM + kh * 32 + fh * 8);
    qhi[kh] = *(const f16x8*)(Qb + (size_t)(qt_hi + fl) * DM + kh * 32 + fh * 8);
#pragma unroll
    for (int j = 0; j < 8; ++j) { qlo[kh][j] *= hs; qhi[kh][j] *= hs; }
  }

  f32x4 o_lo[4] = {}, o_hi[4] = {};
  float m_lo = NEG_BIG, l_lo = 0.f, m_hi = NEG_BIG, l_hi = 0.f;

  const int sr = tid >> 3, e = tid & 7, sc8 = e * 8;
  const int cmax = 15 - p;

  // prologue: load chunk 0 and stage it into buf 0
  f16x8 k0v = *(const f16x8*)(Kb + (size_t)(sr) * DM + sc8);
  f16x8 k1v = *(const f16x8*)(Kb + (size_t)(64 + sr) * DM + sc8);
  f16x8 v0v = *(const f16x8*)(Vb + (size_t)(sr) * DM + sc8);
  f16x8 v1v = *(const f16x8*)(Vb + (size_t)(64 + sr) * DM + sc8);
  *(f16x8*)(&Ks[0][sr][sc8]) = k0v;
  *(f16x8*)(&Ks[0][64 + sr][sc8]) = k1v;
#pragma unroll
  for (int t = 0; t < 8; ++t) {
    const int jj = (t + e) & 7;       // 2 lanes share a dword: free 2-way
    Vt[0][sc8 + jj][sr] = v0v[jj];
    Vt[0][sc8 + jj][64 + sr] = v1v[jj];
  }

  for (int c = 0; c <= cmax; ++c) {
    const int buf = c & 1;
    const int kv0 = c * 128;
    __syncthreads();                  // buf[c&1] writes visible to all waves

    if (c < cmax) {  // T14: issue next chunk's loads; land under compute
      const int kn = kv0 + 128;
      k0v = *(const f16x8*)(Kb + (size_t)(kn + sr) * DM + sc8);
      k1v = *(const f16x8*)(Kb + (size_t)(kn + 64 + sr) * DM + sc8);
      v0v = *(const f16x8*)(Vb + (size_t)(kn + sr) * DM + sc8);
      v1v = *(const f16x8*)(Vb + (size_t)(kn + 64 + sr) * DM + sc8);
    }

    {
      f32x4 s[8];
      qk_tile(Ks[buf], qhi, s, fl, fh);
      sm_pv(Vt[buf], s, o_hi, m_hi, l_hi, kv0, qt_hi + fl, c == cmax, fl, fh);
    }
    if (c <= p) {
      f32x4 s[8];
      qk_tile(Ks[buf], qlo, s, fl, fh);
      sm_pv(Vt[buf], s, o_lo, m_lo, l_lo, kv0, qt_lo + fl, c == p, fl, fh);
    }

    if (c < cmax) {  // stage chunk c+1 into the alternate buffer
      const int nb = buf ^ 1;
      *(f16x8*)(&Ks[nb][sr][sc8]) = k0v;
      *(f16x8*)(&Ks[nb][64 + sr][sc8]) = k1v;
#pragma unroll
      for (int t = 0; t < 8; ++t) {
        const int jj = (t + e) & 7;
        Vt[nb][sc8 + jj][sr] = v0v[jj];
        Vt[nb][sc8 + jj][64 + sr] = v1v[jj];
      }
    }
  }

  // epilogue: O[q][d] from O^T C-layout (d = mt*16 + fh*4 + r contiguous in r)
  {
    const float il = 1.0f / l_lo;
    _Float16* Op = O + ((size_t)b * SEQ + qt_lo + fl) * DM + h * HD;
#pragma unroll
    for (int mt = 0; mt < 4; ++mt) {
      f16x4 ov = {(_Float16)(o_lo[mt][0] * il), (_Float16)(o_lo[mt][1] * il),
                  (_Float16)(o_lo[mt][2] * il), (_Float16)(o_lo[mt][3] * il)};
      *(f16x4*)(Op + mt * 16 + fh * 4) = ov;
    }
  }
  {
    const float il = 1.0f / l_hi;
    _Float16* Op = O + ((size_t)b * SEQ + qt_hi + fl) * DM + h * HD;
#pragma unroll
    for (int mt = 0; mt < 4; ++mt) {
      f16x4 ov = {(_Float16)(o_hi[mt][0] * il), (_Float16)(o_hi[mt][1] * il),
                  (_Float16)(o_hi[mt][2] * il), (_Float16)(o_hi[mt][3] * il)};
      *(f16x4*)(Op + mt * 16 + fh * 4) = ov;
    }
  }
}

// ---------------------------------------------------------------------------
extern "C" void kernel_launch(void* const* d_in, const int* in_sizes, int n_in,
                              void* d_out, int out_size, void* d_ws, size_t ws_size,
                              hipStream_t stream) {
  const float* x = (const float*)d_in[0];
  const float* qw = (const float*)d_in[1];
  const float* kw = (const float*)d_in[2];
  const float* vw = (const float*)d_in[3];
  const float* ow = (const float*)d_in[4];
  float* out = (float*)d_out;

  const size_t MD = (size_t)MTOT * DM;  // 4M elements
  _Float16* x16 = (_Float16*)d_ws;      // [0, 4M) ; later reused as attention M
  _Float16* wT = x16 + MD;              // [4M, 8M): qwT,kwT,vwT,owT
  _Float16* Qw = wT + 4 * (size_t)DM * DM;  // [8M, 12M)
  _Float16* Kw = Qw + MD;               // [12M, 16M)
  _Float16* Vw = Kw + MD;               // [16M, 20M)
  _Float16* Mw = x16;                   // attention output reuses x16
  float* tb = out;                      // RoPE table borrows d_out (512 KB);
                                        // out-proj later overwrites all of out

  prep<<<dim3(16, 16, 7), 256, 0, stream>>>(x, qw, kw, vw, ow, x16, wT, tb);

  // Fused QKV (N = 3072) with RoPE applied to Q,K in the epilogue (table)
  gemm_t<128, 128, true, false, true><<<dim3(24, MTOT / 128), 256, 0, stream>>>(
      x16, wT, Qw, tb, MTOT, DM);

  attn_kernel<<<dim3(8, 32), 512, 0, stream>>>(Qw, Kw, Vw, Mw);

  // Out projection: 64x128 tiles -> 512 blocks (2/CU)
  gemm_t<64, 128, false, true, false><<<dim3(8, MTOT / 64), 256, 0, stream>>>(
      Mw, wT + 3 * (size_t)DM * DM, out, nullptr, MTOT, DM);
}